// Round 4
// baseline (150.303 us; speedup 1.0000x reference)
//
#include <hip/hip_runtime.h>

// CRS rate-and-state model: per-row recurrence parallelized via Mobius map
// composition (R -> et*R/(1+c*R); maps [[a,0],[c,1]] compose associatively).
// One wave per row, 64 lanes x 8 steps = 512-step tiles, wave shuffle-scan.
// R4: replay loop replaced by CLOSED-FORM per-step outputs from within-lane
// inclusive prefixes (A_j,C_j):  R_j = A_j*R~/(1+C_j*R~),
// den_j = 1 + c_j*R_{j-1} -> all 8 divides + 8 logs independent (was a
// ~300-cycle serial fma->log->div chain). LDS bounce dropped (2.1M bank
// conflict cycles, no WRITE_SIZE gain). __launch_bounds__(256,4) raises the
// VGPR cap to 128 so prefetch + coefficient arrays live in registers.

#define C_TNSR  0.001f
#define C_TSSR  0.002f
#define C_SIGMA 50.0f
#define C_BIOT  0.3f
#define C_R0    0.0001f
#define C_N0    0.0001f

constexpr int B = 8192;
constexpr int T = 4096;
constexpr int STEPS = 8;
constexpr int TILE  = 64 * STEPS;   // 512
constexpr int NTILE = T / TILE;     // 8

typedef float f4 __attribute__((ext_vector_type(4)));

__global__ __launch_bounds__(256, 4)
void crs_scan_kernel(const float* __restrict__ params,
                     const float* __restrict__ p,
                     const float* __restrict__ dpdt,
                     const float* __restrict__ dtv,
                     float* __restrict__ Rt,
                     float* __restrict__ Nt)
{
    const int lane = threadIdx.x & 63;
    const int b    = (int)((blockIdx.x * blockDim.x + threadIdx.x) >> 6);

    const float mu  = params[b * 3 + 0];
    const float rc  = params[b * 3 + 1];
    const float rf  = params[b * 3 + 2];
    const float eta = 1.0f / rf;
    const float rcS = rc * C_SIGMA;     // asig = rcS - rcB*p  (one fma)
    const float rcB = rc * C_BIOT;

    const float* __restrict__ prow = p    + (size_t)b * T;
    const float* __restrict__ drow = dpdt + (size_t)b * T;
    const float* __restrict__ trow = dtv  + (size_t)b * T;
    float* __restrict__ Rrow = Rt + (size_t)b * (T + 1) + 1;
    float* __restrict__ Nrow = Nt + (size_t)b * (T + 1) + 1;

    if (lane == 0) { Rrow[-1] = C_R0; Nrow[-1] = C_N0; }

    float Rc = C_R0;   // running R carry
    float Nc = C_N0;   // running Nt cumsum carry (incl. N0)

    const int l8 = lane * STEPS;

    // current-tile input registers
    f4 p0 = *(const f4*)(prow + l8);
    f4 p1 = *(const f4*)(prow + l8 + 4);
    f4 d0 = *(const f4*)(drow + l8);
    f4 d1 = *(const f4*)(drow + l8 + 4);
    f4 t0 = *(const f4*)(trow + l8);
    f4 t1 = *(const f4*)(trow + l8 + 4);

    for (int tile = 0; tile < NTILE; ++tile) {
        const int off = tile * TILE + l8;

        // ---- prefetch next tile; pin issue point ----
        const int noff = (tile + 1 < NTILE) ? (off + TILE) : off;
        f4 np0 = *(const f4*)(prow + noff);
        f4 np1 = *(const f4*)(prow + noff + 4);
        f4 nd0 = *(const f4*)(drow + noff);
        f4 nd1 = *(const f4*)(drow + noff + 4);
        f4 nt0 = *(const f4*)(trow + noff);
        f4 nt1 = *(const f4*)(trow + noff + 4);
        __builtin_amdgcn_sched_barrier(0);

        // ---- coefficients + within-lane inclusive Mobius prefixes ----
        float cc[STEPS], kk[STEPS], Aj[STEPS], Cj[STEPS];
        float A = 1.0f, C = 0.0f;
#pragma unroll
        for (int j = 0; j < STEPS; ++j) {
            float pv = (j < 4) ? p0[j] : p1[j - 4];
            float dv = (j < 4) ? d0[j] : d1[j - 4];
            float tv = (j < 4) ? t0[j] : t1[j - 4];
            float sd   = C_TSSR - mu * (C_TNSR - dv);
            float asig = fmaf(-rcB, pv, rcS);
            float e    = __expf(__fdividef(sd * tv, asig));
            cc[j] = __fdividef(eta * (e - 1.0f), sd);
            kk[j] = asig * rf;               // asig/eta
            C = fmaf(cc[j], A, C);           // compose step j after (A,C)
            A = A * e;
            Aj[j] = A;
            Cj[j] = C;
        }

        // ---- wave-inclusive scan of (A,C): A=A*Ap ; C=C*Ap+Cp ----
#pragma unroll
        for (int o = 1; o < 64; o <<= 1) {
            float Ap = __shfl_up(A, (unsigned)o, 64);
            float Cp = __shfl_up(C, (unsigned)o, 64);
            if (lane >= o) { C = fmaf(C, Ap, Cp); A = A * Ap; }
        }
        float Ae = __shfl_up(A, 1u, 64);
        float Ce = __shfl_up(C, 1u, 64);
        if (lane == 0) { Ae = 1.0f; Ce = 0.0f; }

        // R entering this lane's 8-step segment
        float R0l = __fdividef(Ae * Rc, fmaf(Ce, Rc, 1.0f));

        // ---- closed-form outputs: all divides/logs independent ----
        float Rv[STEPS];
#pragma unroll
        for (int j = 0; j < STEPS; ++j)
            Rv[j] = __fdividef(Aj[j] * R0l, fmaf(Cj[j], R0l, 1.0f));

        float nv[STEPS];
#pragma unroll
        for (int j = 0; j < STEPS; ++j) {
            float Rprev = (j == 0) ? R0l : Rv[j - 1];
            float den   = fmaf(cc[j], Rprev, 1.0f);  // == 1-(eta*R/sd)*(1-et)
            nv[j] = kk[j] * __logf(den);
        }
        float nn[STEPS];
        float ns = 0.0f;
#pragma unroll
        for (int j = 0; j < STEPS; ++j) { ns += nv[j]; nn[j] = ns; }

        // ---- wave prefix sum of per-lane N totals ----
        float S = ns;
#pragma unroll
        for (int o = 1; o < 64; o <<= 1) {
            float Sp = __shfl_up(S, (unsigned)o, 64);
            if (lane >= o) S += Sp;
        }
        float base = Nc + (S - ns);

#pragma unroll
        for (int j = 0; j < STEPS; ++j) {
            Rrow[off + j] = Rv[j];
            Nrow[off + j] = base + nn[j];
        }

        // ---- carries from lane 63, rotate prefetched inputs in ----
        Rc = __shfl(Rv[STEPS - 1], 63, 64);
        Nc = Nc + __shfl(S, 63, 64);
        p0 = np0; p1 = np1; d0 = nd0; d1 = nd1; t0 = nt0; t1 = nt1;
    }
}

extern "C" void kernel_launch(void* const* d_in, const int* in_sizes, int n_in,
                              void* d_out, int out_size, void* d_ws, size_t ws_size,
                              hipStream_t stream)
{
    const float* params = (const float*)d_in[0];
    const float* p      = (const float*)d_in[1];
    const float* dpdt   = (const float*)d_in[2];
    const float* dtv    = (const float*)d_in[3];

    float* Rt = (float*)d_out;                       // B*(T+1)
    float* Nt = (float*)d_out + (size_t)B * (T + 1); // B*(T+1)

    const int block = 256;                 // 4 waves = 4 rows per block
    const int grid  = (B * 64) / block;    // 2048 blocks
    crs_scan_kernel<<<grid, block, 0, stream>>>(params, p, dpdt, dtv, Rt, Nt);
}